// Round 5
// baseline (160.153 us; speedup 1.0000x reference)
//
#include <hip/hip_runtime.h>
#include <stdint.h>

#define B_ 4
#define S_ 2048
#define D_ 768
#define U_ 768

typedef __bf16 bf16x8 __attribute__((ext_vector_type(8)));
typedef float f32x4 __attribute__((ext_vector_type(4)));

#define AS1 __attribute__((address_space(1)))
#define AS3 __attribute__((address_space(3)))

#define BAR() __builtin_amdgcn_s_barrier()
#define WAITV6() asm volatile("s_waitcnt vmcnt(6)" ::: "memory")
#define WAITV5() asm volatile("s_waitcnt vmcnt(5)" ::: "memory")
#define WAITV0() asm volatile("s_waitcnt vmcnt(0)" ::: "memory")
#define PRIO(x) __builtin_amdgcn_s_setprio(x)

__device__ __forceinline__ ushort f2bf(float f) {
    union { float f; uint32_t u; } v; v.f = f;
    uint32_t r = v.u + 0x7fffu + ((v.u >> 16) & 1u);
    return (ushort)(r >> 16);
}

__device__ __forceinline__ void gload_lds16(const void* gp, void* lp) {
    // width-16 global->LDS: HW scatters to (wave-uniform lds base) + lane*16
    __builtin_amdgcn_global_load_lds((AS1 void*)gp, (AS3 void*)lp, 16, 0, 0);
}

// ============================================================================
// Fused QKV projection: one block computes a 128-row A-panel against Wq, Wk,
// Wv 256-col panels (A staged once, reused 3x -> 112 FLOP/B). BK=32, 8 waves
// (2M x 4N, per-wave 64x64 per z). 3 compute phases per K-tile (z=0,1,2),
// 16 MFMA each. Triple-buffered A, double-buffered B[z].
// LDS (ushort elems): A: 3 x 4096 @ 0; B[z]: 2 x 8192 @ 12288 + z*16384.
// Total 122880 B.
// BK=32 swizzle: row = 64B = 4 x 16B slots; slot ^= sw(r), sw(r) =
// (r&3)^((r>>2)&3) -> each bank hit by exactly 2 lanes (free, m136).
// Pipeline per tile t (c=t&1, ab=t%3):
//   p0: LDA(ab)+LDB0(c); stage Bv(t+1)->bv[c^1], A(t+2)->a[(t+2)%3]
//   p1: LDB1(c); stage Bq(t+2)->bq[c]
//   p2: LDB2(c); stage Bk(t+2)->bk[c]; vmcnt(5) [keeps A,Bq,Bk of t+2]
// Distances: A(t+2) forced end(t+1) ~ 2 tiles (HBM-safe); B* >= 1 tile (L2).
// WAR: every buffer's overwrite-issue is >=1 barrier after its lgkm-guarded
// final read (Bv consumed p2(t-1), written p0(t); Bq p0->p1; Bk p1->p2;
// A read p0(t-1), written p0(t+... same index 3 tiles later).
// ============================================================================
__global__ __launch_bounds__(512, 2) void proj_fused_kernel(
    const ushort* __restrict__ xb, const ushort* __restrict__ Wt,
    ushort* __restrict__ Qb, ushort* __restrict__ Kb, ushort* __restrict__ Vt) {
    extern __shared__ ushort sm[];
    const int b0 = blockIdx.x;                      // 192 blocks
    const int wg = (b0 & 7) * 24 + (b0 >> 3);       // XCD-contiguous ty-chunks
    const int ty = wg / 3, tx = wg % 3;
    const int M0 = ty * 128, N0 = tx * 256;
    constexpr int NT = D_ / 32;                     // 24

    const int tid = threadIdx.x;
    const int l = tid & 63, w = tid >> 6;
    const int lr = l & 15, lg = l >> 4;
    const int wm = w >> 2, wn = w & 3;
    const int swl = (lr & 3) ^ ((lr >> 2) & 3);     // read-side slot swizzle

    f32x4 acc[3][4][4];
#pragma unroll
    for (int z = 0; z < 3; ++z)
#pragma unroll
        for (int m = 0; m < 4; ++m)
#pragma unroll
            for (int n = 0; n < 4; ++n)
                acc[z][m][n] = (f32x4){0.f, 0.f, 0.f, 0.f};

    // stage A (128x32, 8KB, 1 load/thread) of K-tile kt into a-buf ab
    auto STA = [&](int ab, int kt) {
        int c = w * 64 + l;
        int r = c >> 2, sl = c & 3;
        int swr = (r & 3) ^ ((r >> 2) & 3);
        gload_lds16(xb + (size_t)(M0 + r) * D_ + kt * 32 + ((sl ^ swr) << 3),
                    sm + ab * 4096 + w * 512);
    };
    // stage B[z] (256x32, 16KB, 2 loads/thread) of K-tile kt into b-buf
    auto STB = [&](int z, int buf, int kt) {
        const ushort* Wz = Wt + (size_t)z * U_ * D_;
        ushort* dstb = sm + 12288 + z * 16384 + buf * 8192;
#pragma unroll
        for (int j = 0; j < 2; ++j) {
            int c = j * 512 + w * 64 + l;
            int r = c >> 2, sl = c & 3;
            int swr = (r & 3) ^ ((r >> 2) & 3);
            gload_lds16(Wz + (size_t)(N0 + r) * D_ + kt * 32 + ((sl ^ swr) << 3),
                        dstb + j * 4096 + w * 512);
        }
    };

    bf16x8 afr[4], bfr[4];
    auto LDA = [&](int ab) {
#pragma unroll
        for (int mf = 0; mf < 4; ++mf) {
            int r = wm * 64 + mf * 16 + lr;
            afr[mf] = *(const bf16x8*)((const char*)sm + ab * 8192 + r * 64 +
                                       ((lg ^ swl) << 4));
        }
    };
    auto LDB = [&](int z, int buf) {
#pragma unroll
        for (int nf = 0; nf < 4; ++nf) {
            int r = wn * 64 + nf * 16 + lr;
            bfr[nf] = *(const bf16x8*)((const char*)sm + 24576 + z * 32768 +
                                       buf * 16384 + r * 64 + ((lg ^ swl) << 4));
        }
    };

#define MMZ(Z)                                                                 \
    PRIO(1);                                                                   \
    _Pragma("unroll")                                                          \
    for (int mf = 0; mf < 4; ++mf)                                             \
        _Pragma("unroll")                                                      \
        for (int nf = 0; nf < 4; ++nf)                                         \
            acc[Z][mf][nf] = __builtin_amdgcn_mfma_f32_16x16x32_bf16(          \
                afr[mf], bfr[nf], acc[Z][mf][nf], 0, 0, 0);                    \
    PRIO(0);

    // prologue: tile0 fully (7 loads) + A(1),Bq(1),Bk(1) (5 loads)
    STA(0, 0); STB(0, 0, 0); STB(1, 0, 0); STB(2, 0, 0);
    STA(1, 1); STB(0, 1, 1); STB(1, 1, 1);
    WAITV5();
    BAR();

    for (int t = 0; t < NT; ++t) {
        const int c = t & 1, ab = t % 3;
        // phase 0: z=0 (Q)
        LDA(ab); LDB(0, c);
        if (t + 1 < NT) STB(2, c ^ 1, t + 1);       // Bv(t+1), issued first
        if (t + 2 < NT) STA((t + 2) % 3, t + 2);
        BAR();
        MMZ(0);
        BAR();
        // phase 1: z=1 (K)
        LDB(1, c);
        if (t + 2 < NT) STB(0, c, t + 2);
        BAR();
        MMZ(1);
        BAR();
        // phase 2: z=2 (V)
        LDB(2, c);
        if (t + 2 < NT) STB(1, c, t + 2);
        BAR();
        MMZ(2);
        if (t + 2 < NT) { WAITV5(); } else { WAITV0(); }
        BAR();
    }
#undef MMZ

    // epilogue: C/D frag mapping col = lane&15, row = (lane>>4)*4 + i
#pragma unroll
    for (int z = 0; z < 3; ++z) {
#pragma unroll
        for (int mf = 0; mf < 4; ++mf) {
#pragma unroll
            for (int nf = 0; nf < 4; ++nf) {
#pragma unroll
                for (int i = 0; i < 4; ++i) {
                    int r = M0 + wm * 64 + mf * 16 + lg * 4 + i;
                    int cc = N0 + wn * 64 + nf * 16 + lr;
                    ushort v = f2bf(acc[z][mf][nf][i]);
                    if (z == 0) {
                        Qb[(size_t)r * U_ + cc] = v;
                    } else if (z == 1) {
                        Kb[(size_t)r * U_ + cc] = v;
                    } else {
                        int b = r >> 11, s = r & 2047;
                        Vt[((size_t)b * U_ + cc) * S_ + s] = v;
                    }
                }
            }
        }
    }
}

// ============================================================================
// 256x256 8-phase pipelined GEMM (proven r2 path — scores only).
// ============================================================================
__device__ __forceinline__ void gemm256(
    ushort* sm,
    const ushort* __restrict__ Ag, int lda,
    const ushort* __restrict__ Btg, int ldb,
    float* __restrict__ Cp, int ldc, int Kd, float scale,
    int ty, int tx)
{
    constexpr int ABUF = 256 * 64;
    ushort* sA = sm;
    ushort* sB = sm + 2 * ABUF;

    const int tid = threadIdx.x;
    const int l = tid & 63, w = tid >> 6;
    const int lr = l & 15, lg = l >> 4;
    const int wm = w >> 2, wn = w & 3;
    const int M0 = ty * 256, N0 = tx * 256;

    f32x4 acc[8][4];
#pragma unroll
    for (int m = 0; m < 8; ++m)
#pragma unroll
        for (int n = 0; n < 4; ++n)
            acc[m][n] = (f32x4){0.f, 0.f, 0.f, 0.f};

    const int NT = Kd >> 6;

    auto STA = [&](int buf, int qp, int kt) {
#pragma unroll
        for (int j = 0; j < 2; ++j) {
            int q = qp + j;
            int r0 = (w < 4) ? (q * 32 + w * 8) : (128 + q * 32 + (w - 4) * 8);
            int r = r0 + (l >> 3);
            int lc = ((l & 7) * 16) ^ ((r & 7) << 4);
            gload_lds16(Ag + (size_t)(M0 + r) * lda + kt * 64 + (lc >> 1),
                        sA + buf * ABUF + r0 * 64);
        }
    };
    auto STB = [&](int buf, int h, int kt) {
#pragma unroll
        for (int j = 0; j < 2; ++j) {
            int r0 = h * 128 + j * 64 + w * 8;
            int r = r0 + (l >> 3);
            int lc = ((l & 7) * 16) ^ ((r & 7) << 4);
            gload_lds16(Btg + (size_t)(N0 + r) * ldb + kt * 64 + (lc >> 1),
                        sB + buf * 16384 + r0 * 64);
        }
    };

    bf16x8 afr[2][2], bfr[4][2];
    auto LDB = [&](int buf) {
#pragma unroll
        for (int nf = 0; nf < 4; ++nf)
#pragma unroll
            for (int ks = 0; ks < 2; ++ks) {
                int r = wn * 64 + nf * 16 + lr;
                int off = r * 128 + ((ks * 64 + lg * 16) ^ ((r & 7) << 4));
                bfr[nf][ks] = *(const bf16x8*)((const char*)(sB + buf * 16384) + off);
            }
    };
    auto LDA = [&](int buf, int q) {
#pragma unroll
        for (int j = 0; j < 2; ++j)
#pragma unroll
            for (int ks = 0; ks < 2; ++ks) {
                int r = wm * 128 + (2 * q + j) * 16 + lr;
                int off = r * 128 + ((ks * 64 + lg * 16) ^ ((r & 7) << 4));
                afr[j][ks] = *(const bf16x8*)((const char*)(sA + buf * ABUF) + off);
            }
    };

#define MMQ(Q)                                                                 \
    PRIO(1);                                                                   \
    _Pragma("unroll")                                                          \
    for (int j = 0; j < 2; ++j)                                                \
        _Pragma("unroll")                                                      \
        for (int nf = 0; nf < 4; ++nf)                                         \
            _Pragma("unroll")                                                  \
            for (int ks = 0; ks < 2; ++ks)                                     \
                acc[2 * (Q) + j][nf] = __builtin_amdgcn_mfma_f32_16x16x32_bf16(\
                    afr[j][ks], bfr[nf][ks], acc[2 * (Q) + j][nf], 0, 0, 0);   \
    PRIO(0);

    STA(0, 0, 0); STA(0, 2, 0); STB(0, 0, 0); STB(0, 1, 0);
    if (NT > 1) {
        STB(1, 0, 1); STB(1, 1, 1); STA(1, 0, 1);
        WAITV6();
    } else {
        WAITV0();
    }
    BAR();

    for (int t = 0; t < NT; ++t) {
        const int c = t & 1;
        LDB(c); LDA(c, 0);
        if (t + 1 < NT) STA(c ^ 1, 2, t + 1);
        BAR();
        MMQ(0);
        BAR();
        LDA(c, 1);
        if (t + 2 < NT) STB(c, 0, t + 2);
        BAR();
        MMQ(1);
        BAR();
        LDA(c, 2);
        if (t + 2 < NT) STB(c, 1, t + 2);
        BAR();
        MMQ(2);
        BAR();
        LDA(c, 3);
        if (t + 2 < NT) STA(c, 0, t + 2);
        BAR();
        MMQ(3);
        if (t + 2 < NT) { WAITV6(); } else { WAITV0(); }
        BAR();
    }
#undef MMQ

#pragma unroll
    for (int mf = 0; mf < 8; ++mf)
#pragma unroll
        for (int nf = 0; nf < 4; ++nf)
#pragma unroll
            for (int i = 0; i < 4; ++i) {
                int r = M0 + wm * 128 + mf * 16 + lg * 4 + i;
                int c = N0 + wn * 64 + nf * 16 + lr;
                Cp[(size_t)r * ldc + c] = acc[mf][nf][i] * scale;
            }
}

__global__ __launch_bounds__(512) void scores_kernel(
    const ushort* __restrict__ Qb, const ushort* __restrict__ Kb,
    float* __restrict__ Sc, float scale) {
    extern __shared__ ushort sm[];
    const int nwg = gridDim.x;                       // 256 or 64, %8==0
    const int b0 = blockIdx.x;
    const int wg = (b0 & 7) * (nwg >> 3) + (b0 >> 3);
    const int tx = wg & 7, ty = (wg >> 3) & 7, z = wg >> 6;
    gemm256(sm, Qb + (size_t)z * S_ * U_, U_, Kb + (size_t)z * S_ * U_, U_,
            Sc + (size_t)z * S_ * S_, S_, U_, scale, ty, tx);
}

// ============================================================================
// PV: 128x256 2-compute-phase GEMM with TRIPLE-buffered A (deep prefetch for
// the HBM-streamed P operand). BK=64, 8 waves 2Mx4N, 16 MFMA/phase.
// LDS: sA 3 x 8192 elems @ 0; sB 2 x 16384 elems @ 24576. Total 114688 B.
// Per tile t (c=t&1, ab=t%3):
//   p0: LDB(c)+LDA(ab,h0); stage A(t+2)->a[(t+2)%3]  (2 loads)
//   p1: LDA(ab,h1); stage B(t+2)->b[c]               (4 loads)
//   end: vmcnt(6) keeps {A(t+2),B(t+2)}; A forced end(t+1) ~ 2 tiles.
// ============================================================================
__global__ __launch_bounds__(512) void pv_kernel(
    const ushort* __restrict__ P, const ushort* __restrict__ Vt,
    float* __restrict__ out) {
    extern __shared__ ushort sm[];
    const int b0 = blockIdx.x;                      // 192 blocks
    const int wg = (b0 & 7) * 24 + (b0 >> 3);
    const int z = wg / 48, rem = wg % 48;
    const int ty = rem / 3, tx = rem % 3;
    const ushort* Ag = P + (size_t)z * S_ * S_;
    const ushort* Btg = Vt + (size_t)z * U_ * S_;
    float* Cp = out + (size_t)z * S_ * U_;
    const int M0 = ty * 128, N0 = tx * 256;
    constexpr int NT = S_ / 64;                     // 32
    constexpr int ABUF = 128 * 64;                  // 8192 elems

    const int tid = threadIdx.x;
    const int l = tid & 63, w = tid >> 6;
    const int lr = l & 15, lg = l >> 4;
    const int wm = w >> 2, wn = w & 3;

    f32x4 acc[4][4];
#pragma unroll
    for (int m = 0; m < 4; ++m)
#pragma unroll
        for (int n = 0; n < 4; ++n)
            acc[m][n] = (f32x4){0.f, 0.f, 0.f, 0.f};

    auto STA = [&](int ab, int kt) {
#pragma unroll
        for (int j = 0; j < 2; ++j) {
            int r0 = w * 16 + j * 8;
            int r = r0 + (l >> 3);
            int lc = ((l & 7) * 16) ^ ((r & 7) << 4);
            gload_lds16(Ag + (size_t)(M0 + r) * S_ + kt * 64 + (lc >> 1),
                        sm + ab * ABUF + r0 * 64);
        }
    };
    auto STB = [&](int buf, int h, int kt) {
#pragma unroll
        for (int j = 0; j < 2; ++j) {
            int r0 = h * 128 + j * 64 + w * 8;
            int r = r0 + (l >> 3);
            int lc = ((l & 7) * 16) ^ ((r & 7) << 4);
            gload_lds16(Btg + (size_t)(N0 + r) * S_ + kt * 64 + (lc >> 1),
                        sm + 24576 + buf * 16384 + r0 * 64);
        }
    };

    bf16x8 afr[2][2], bfr[4][2];
    auto LDB = [&](int buf) {
#pragma unroll
        for (int nf = 0; nf < 4; ++nf)
#pragma unroll
            for (int ks = 0; ks < 2; ++ks) {
                int r = wn * 64 + nf * 16 + lr;
                int off = r * 128 + ((ks * 64 + lg * 16) ^ ((r & 7) << 4));
                bfr[nf][ks] = *(const bf16x8*)((const char*)(sm + 24576 + buf * 16384) + off);
            }
    };
    auto LDA2 = [&](int ab, int h) {
#pragma unroll
        for (int j = 0; j < 2; ++j)
#pragma unroll
            for (int ks = 0; ks < 2; ++ks) {
                int r = wm * 64 + (2 * h + j) * 16 + lr;
                int off = r * 128 + ((ks * 64 + lg * 16) ^ ((r & 7) << 4));
                afr[j][ks] = *(const bf16x8*)((const char*)(sm + ab * ABUF) + off);
            }
    };

#define MMH(H)                                                                 \
    PRIO(1);                                                                   \
    _Pragma("unroll")                                                          \
    for (int j = 0; j < 2; ++j)                                                \
        _Pragma("unroll")                                                      \
        for (int nf = 0; nf < 4; ++nf)                                         \
            _Pragma("unroll")                                                  \
            for (int ks = 0; ks < 2; ++ks)                                     \
                acc[2 * (H) + j][nf] = __builtin_amdgcn_mfma_f32_16x16x32_bf16(\
                    afr[j][ks], bfr[nf][ks], acc[2 * (H) + j][nf], 0, 0, 0);   \
    PRIO(0);

    // prologue: A(0),B(0),A(1),B(1) = 12 loads; keep {A(1),B(1)} = 6
    STA(0, 0); STB(0, 0, 0); STB(0, 1, 0);
    STA(1, 1); STB(1, 0, 1); STB(1, 1, 1);
    WAITV6();
    BAR();

    for (int t = 0; t < NT; ++t) {
        const int c = t & 1, ab = t % 3;
        // phase 0
        LDB(c); LDA2(ab, 0);
        if (t + 2 < NT) STA((t + 2) % 3, t + 2);
        BAR();
        MMH(0);
        BAR();
        // phase 1
        LDA2(ab, 1);
        if (t + 2 < NT) { STB(c, 0, t + 2); STB(c, 1, t + 2); }
        BAR();
        MMH(1);
        if (t + 2 < NT) { WAITV6(); } else { WAITV0(); }
        BAR();
    }
#undef MMH

#pragma unroll
    for (int mf = 0; mf < 4; ++mf)
#pragma unroll
        for (int nf = 0; nf < 4; ++nf)
#pragma unroll
            for (int i = 0; i < 4; ++i) {
                int r = M0 + wm * 64 + mf * 16 + lg * 4 + i;
                int c = N0 + wn * 64 + nf * 16 + lr;
                Cp[(size_t)r * U_ + c] = acc[mf][nf][i];
            }
}

// ======================= small helper kernels ========================

__global__ void cast_x_kernel(const float4* __restrict__ in,
                              ushort4* __restrict__ out, int n4) {
    int i = blockIdx.x * 256 + threadIdx.x;
    if (i >= n4) return;
    float4 v = in[i];
    ushort4 o;
    o.x = f2bf(v.x); o.y = f2bf(v.y); o.z = f2bf(v.z); o.w = f2bf(v.w);
    out[i] = o;
}

__global__ void transpose_w_kernel(const float* __restrict__ Wq,
                                   const float* __restrict__ Wk,
                                   const float* __restrict__ Wv,
                                   ushort* __restrict__ Wt) {
    const float* W = blockIdx.z == 0 ? Wq : (blockIdx.z == 1 ? Wk : Wv);
    __shared__ float t[32][33];
    int x0 = blockIdx.x * 32, y0 = blockIdx.y * 32;
    int tx = threadIdx.x;
    for (int i = threadIdx.y; i < 32; i += 8)
        t[i][tx] = W[(size_t)(y0 + i) * U_ + (x0 + tx)];
    __syncthreads();
    ushort* Wtz = Wt + (size_t)blockIdx.z * U_ * D_;
    for (int i = threadIdx.y; i < 32; i += 8)
        Wtz[(size_t)(x0 + i) * D_ + (y0 + tx)] = f2bf(t[tx][i]);
}

__global__ __launch_bounds__(256) void softmax_kernel(
    const float* __restrict__ Sc, ushort* __restrict__ P) {
    size_t row = (size_t)blockIdx.y * gridDim.x + blockIdx.x;
    const float4* r4 = (const float4*)(Sc + row * S_);
    int t = threadIdx.x;
    int w = t >> 6, l = t & 63;
    float4 a = r4[t], b = r4[t + 256];
    float mx = fmaxf(fmaxf(fmaxf(a.x, a.y), fmaxf(a.z, a.w)),
                     fmaxf(fmaxf(b.x, b.y), fmaxf(b.z, b.w)));
#pragma unroll
    for (int off = 32; off; off >>= 1) mx = fmaxf(mx, __shfl_xor(mx, off));
    __shared__ float red[8];
    if (l == 0) red[w] = mx;
    __syncthreads();
    mx = fmaxf(fmaxf(red[0], red[1]), fmaxf(red[2], red[3]));
    float e[8];
    e[0] = __expf(a.x - mx); e[1] = __expf(a.y - mx);
    e[2] = __expf(a.z - mx); e[3] = __expf(a.w - mx);
    e[4] = __expf(b.x - mx); e[5] = __expf(b.y - mx);
    e[6] = __expf(b.z - mx); e[7] = __expf(b.w - mx);
    float s = e[0] + e[1] + e[2] + e[3] + e[4] + e[5] + e[6] + e[7];
#pragma unroll
    for (int off = 32; off; off >>= 1) s += __shfl_xor(s, off);
    if (l == 0) red[4 + w] = s;
    __syncthreads();
    float inv = 1.f / (red[4] + red[5] + red[6] + red[7]);
    ushort4* p4 = (ushort4*)(P + row * S_);
    ushort4 o1, o2;
    o1.x = f2bf(e[0] * inv); o1.y = f2bf(e[1] * inv);
    o1.z = f2bf(e[2] * inv); o1.w = f2bf(e[3] * inv);
    o2.x = f2bf(e[4] * inv); o2.y = f2bf(e[5] * inv);
    o2.z = f2bf(e[6] * inv); o2.w = f2bf(e[7] * inv);
    p4[t] = o1; p4[t + 256] = o2;
}

extern "C" void kernel_launch(void* const* d_in, const int* in_sizes, int n_in,
                              void* d_out, int out_size, void* d_ws, size_t ws_size,
                              hipStream_t stream) {
    (void)in_sizes; (void)n_in; (void)out_size;
    const float* x = (const float*)d_in[0];
    const float* Wq = (const float*)d_in[1];
    const float* Wk = (const float*)d_in[2];
    const float* Wv = (const float*)d_in[3];
    float* out = (float*)d_out;

    char* ws = (char*)d_ws;
    size_t off = 0;
    auto alloc = [&](size_t bytes) -> void* {
        void* p = ws + off;
        off += (bytes + 255) & ~(size_t)255;
        return p;
    };
    ushort* xb = (ushort*)alloc((size_t)B_ * S_ * D_ * 2);
    ushort* Wt = (ushort*)alloc((size_t)3 * U_ * D_ * 2);
    ushort* Qb = (ushort*)alloc((size_t)B_ * S_ * U_ * 2);
    ushort* Kb = (ushort*)alloc((size_t)B_ * S_ * U_ * 2);
    ushort* Vt = (ushort*)alloc((size_t)B_ * S_ * U_ * 2);  // [B][U][S]
    ushort* P  = (ushort*)alloc((size_t)B_ * S_ * S_ * 2);
    bool full = (ws_size - off) >= (size_t)B_ * S_ * S_ * 4 + 256;
    float* Sc = (float*)alloc(full ? (size_t)B_ * S_ * S_ * 4 : (size_t)S_ * S_ * 4);

    hipFuncSetAttribute(reinterpret_cast<const void*>(proj_fused_kernel),
                        hipFuncAttributeMaxDynamicSharedMemorySize, 131072);
    hipFuncSetAttribute(reinterpret_cast<const void*>(scores_kernel),
                        hipFuncAttributeMaxDynamicSharedMemorySize, 131072);
    hipFuncSetAttribute(reinterpret_cast<const void*>(pv_kernel),
                        hipFuncAttributeMaxDynamicSharedMemorySize, 131072);

    int n4 = B_ * S_ * D_ / 4;
    cast_x_kernel<<<(n4 + 255) / 256, 256, 0, stream>>>(
        (const float4*)x, (ushort4*)xb, n4);
    transpose_w_kernel<<<dim3(U_ / 32, D_ / 32, 3), dim3(32, 8), 0, stream>>>(
        Wq, Wk, Wv, Wt);
    proj_fused_kernel<<<192, 512, 122880, stream>>>(xb, Wt, Qb, Kb, Vt);

    const float scale = 0.036084391824351615f;  // 1/sqrt(768)
    if (full) {
        scores_kernel<<<256, 512, 131072, stream>>>(Qb, Kb, Sc, scale);
        softmax_kernel<<<dim3(S_, B_), 256, 0, stream>>>(Sc, P);
    } else {
        for (int b = 0; b < B_; ++b) {
            scores_kernel<<<64, 512, 131072, stream>>>(
                Qb + (size_t)b * S_ * U_, Kb + (size_t)b * S_ * U_, Sc, scale);
            softmax_kernel<<<dim3(S_, 1), 256, 0, stream>>>(
                Sc, P + (size_t)b * S_ * S_);
        }
    }
    pv_kernel<<<192, 512, 114688, stream>>>(P, Vt, out);
}